// Round 8
// baseline (768.837 us; speedup 1.0000x reference)
//
#include <hip/hip_runtime.h>
#include <hip/hip_bf16.h>
#include <hip/hip_fp16.h>

#define NN 50000
#define NE 800000
#define SCAN_NB ((NN + 255) / 256)   // 196

typedef __attribute__((ext_vector_type(8))) short bf16x8;
typedef __attribute__((ext_vector_type(4))) float f32x4;

__device__ __forceinline__ ushort f2bf(float f) {
    __hip_bfloat16 h = __float2bfloat16(f);
    return *reinterpret_cast<ushort*>(&h);
}
__device__ __forceinline__ float bf2f(ushort u) {
    return __builtin_bit_cast(float, (uint)u << 16);
}
__device__ __forceinline__ void split2(float a, float b, uint& hi, uint& lo) {
    ushort ha = f2bf(a), hb = f2bf(b);
    float fa = bf2f(ha), fb = bf2f(hb);
    ushort la = f2bf(a - fa), lb = f2bf(b - fb);
    hi = (uint)ha | ((uint)hb << 16);
    lo = (uint)la | ((uint)lb << 16);
}
__device__ __forceinline__ ushort f2h(float f) {
    __half h = __float2half(f);
    return __builtin_bit_cast(ushort, h);
}
__device__ __forceinline__ float2 h2f2(uint u) {
    __half2 h = __builtin_bit_cast(__half2, u);
    return __half22float2(h);
}

// ---------------------------------------------------------------- zero deg + aggE
__global__ void zero2_kernel(int* __restrict__ deg, float* __restrict__ aggE) {
    int i = blockIdx.x * blockDim.x + threadIdx.x;
    if (i < NN) deg[i] = 0;
    if (i < NN * 8) aggE[i] = 0.f;
}

// ---------------------------------------------------------------- deg + aggE (fused, atomics)
__global__ void deg_agge_kernel(const int* __restrict__ dst, const float* __restrict__ ea,
                                int* __restrict__ deg, float* __restrict__ aggE, int E) {
    int e = blockIdx.x * blockDim.x + threadIdx.x;
    if (e < E) {
        int d = dst[e];
        atomicAdd(&deg[d], 1);
        const float4* q = reinterpret_cast<const float4*>(ea + (size_t)e * 8);
        float4 q0 = q[0], q1 = q[1];
        float* base = aggE + (size_t)d * 8;
        atomicAdd(base + 0, q0.x); atomicAdd(base + 1, q0.y);
        atomicAdd(base + 2, q0.z); atomicAdd(base + 3, q0.w);
        atomicAdd(base + 4, q1.x); atomicAdd(base + 5, q1.y);
        atomicAdd(base + 6, q1.z); atomicAdd(base + 7, q1.w);
    }
}

// ---------------------------------------------------------------- scans
__global__ void scan1_kernel(const int* __restrict__ deg, int* __restrict__ pre,
                             int* __restrict__ bsum) {
    __shared__ int sm[256];
    int t = threadIdx.x;
    int i = blockIdx.x * 256 + t;
    int v = (i < NN) ? deg[i] : 0;
    sm[t] = v;
    __syncthreads();
#pragma unroll
    for (int off = 1; off < 256; off <<= 1) {
        int u = (t >= off) ? sm[t - off] : 0;
        __syncthreads();
        sm[t] += u;
        __syncthreads();
    }
    if (i < NN) pre[i] = sm[t] - v;
    if (t == 255) bsum[blockIdx.x] = sm[255];
}

__global__ void scan2_kernel(const int* __restrict__ bsum, int* __restrict__ boff) {
    __shared__ int sm[256];
    int t = threadIdx.x;
    int v = (t < SCAN_NB) ? bsum[t] : 0;
    sm[t] = v;
    __syncthreads();
#pragma unroll
    for (int off = 1; off < 256; off <<= 1) {
        int u = (t >= off) ? sm[t - off] : 0;
        __syncthreads();
        sm[t] += u;
        __syncthreads();
    }
    if (t < SCAN_NB) boff[t] = sm[t] - v;
}

__global__ void scan3_kernel(int* __restrict__ row_start, const int* __restrict__ boff,
                             int* __restrict__ cursor) {
    int i = blockIdx.x * 256 + threadIdx.x;
    if (i < NN) {
        int r = row_start[i] + boff[blockIdx.x];
        row_start[i] = r;
        cursor[i] = r;
    }
    if (i == 0) row_start[NN] = NE;
}

// fill CSR (csr_src only)
__global__ void fill_kernel(const int* __restrict__ src, const int* __restrict__ dst,
                            int* __restrict__ cursor, int* __restrict__ csr_src, int E) {
    int e = blockIdx.x * blockDim.x + threadIdx.x;
    if (e < E) {
        int d = dst[e];
        int p = atomicAdd(&cursor[d], 1);
        csr_src[p] = src[e];
    }
}

// ---------------------------------------------------------------- weight prep (bf16 hi/lo split)
__global__ void prep_w_kernel(const float* __restrict__ Ws, const float* __restrict__ Wm,
                              ushort* __restrict__ Whi, ushort* __restrict__ Wlo,
                              int DIN, int DOUT, int KPAD) {
    int gid = blockIdx.x * blockDim.x + threadIdx.x;
    if (gid >= DOUT * KPAD) return;
    int c = gid / KPAD, k = gid % KPAD;
    float v = 0.f;
    if (k < DIN) v = Ws[(size_t)k * DOUT + c];
    else if (k < 2 * DIN + 8) v = Wm[(size_t)(k - DIN) * DOUT + c];
    ushort h = f2bf(v);
    Whi[gid] = h;
    Wlo[gid] = f2bf(v - bf2f(h));
}

// ---------------------------------------------------------------- agg_h layer0 (fp32 x, DIN=32)
__global__ void aggh32_kernel(const float* __restrict__ h, const int* __restrict__ row_start,
                              const int* __restrict__ csrc, float* __restrict__ aggH) {
    int w = blockIdx.x * (blockDim.x >> 6) + (threadIdx.x >> 6);
    int lane = threadIdx.x & 63;
    if (w >= NN) return;
    int lo = row_start[w], hi = row_start[w + 1];
    int half = lane >> 5;
    int l32 = lane & 31;
    float a0 = 0.f, a1 = 0.f, a2 = 0.f, a3 = 0.f;
    int j = lo;
    while (j < hi) {
        int cnt = hi - j; if (cnt > 64) cnt = 64;
        int myidx = (lane < cnt) ? csrc[j + lane] : 0;
        int k = 0;
        for (; k + 8 <= cnt; k += 8) {
            int s0 = __shfl(myidx, k + half);
            int s1 = __shfl(myidx, k + 2 + half);
            int s2 = __shfl(myidx, k + 4 + half);
            int s3 = __shfl(myidx, k + 6 + half);
            a0 += h[(size_t)s0 * 32 + l32];
            a1 += h[(size_t)s1 * 32 + l32];
            a2 += h[(size_t)s2 * 32 + l32];
            a3 += h[(size_t)s3 * 32 + l32];
        }
        for (; k + 2 <= cnt; k += 2) {
            int s = __shfl(myidx, k + half);
            a0 += h[(size_t)s * 32 + l32];
        }
        if (k < cnt) {
            int s = __shfl(myidx, k);
            if (half == 0) a1 += h[(size_t)s * 32 + l32];
        }
        j += cnt;
    }
    a0 = (a0 + a1) + (a2 + a3);
    a0 += __shfl_xor(a0, 32);
    if (lane < 32) aggH[(size_t)w * 32 + lane] = a0;
}

// ---------------------------------------------------------------- agg_h fp16 gather (DIN=64/128)
template <int DIN>
__global__ void aggh16_kernel(const ushort* __restrict__ h16, const int* __restrict__ row_start,
                              const int* __restrict__ csrc, float* __restrict__ aggH) {
    int w = blockIdx.x * (blockDim.x >> 6) + (threadIdx.x >> 6);
    int lane = threadIdx.x & 63;
    if (w >= NN) return;
    int lo = row_start[w], hi = row_start[w + 1];
    const uint* H = reinterpret_cast<const uint*>(h16);

    if constexpr (DIN == 128) {
        // full wave per row: 64 lanes x 1 uint (2 halves)
        float2 a0 = {0.f,0.f}, a1 = {0.f,0.f}, a2 = {0.f,0.f}, a3 = {0.f,0.f};
        int j = lo;
        while (j < hi) {
            int cnt = hi - j; if (cnt > 64) cnt = 64;
            int myidx = (lane < cnt) ? csrc[j + lane] : 0;
            int k = 0;
            for (; k + 4 <= cnt; k += 4) {
                int s0 = __shfl(myidx, k);
                int s1 = __shfl(myidx, k + 1);
                int s2 = __shfl(myidx, k + 2);
                int s3 = __shfl(myidx, k + 3);
                float2 v0 = h2f2(H[(size_t)s0 * 64 + lane]);
                float2 v1 = h2f2(H[(size_t)s1 * 64 + lane]);
                float2 v2 = h2f2(H[(size_t)s2 * 64 + lane]);
                float2 v3 = h2f2(H[(size_t)s3 * 64 + lane]);
                a0.x += v0.x; a0.y += v0.y;
                a1.x += v1.x; a1.y += v1.y;
                a2.x += v2.x; a2.y += v2.y;
                a3.x += v3.x; a3.y += v3.y;
            }
            for (; k < cnt; ++k) {
                int s = __shfl(myidx, k);
                float2 v = h2f2(H[(size_t)s * 64 + lane]);
                a0.x += v.x; a0.y += v.y;
            }
            j += cnt;
        }
        a0.x += a1.x; a0.y += a1.y;
        a2.x += a3.x; a2.y += a3.y;
        a0.x += a2.x; a0.y += a2.y;
        reinterpret_cast<float2*>(aggH)[(size_t)w * 64 + lane] = a0;
    } else {  // DIN == 64: half wave per row (32 lanes x 1 uint); 2 rows per pass
        int hf = lane >> 5, l32 = lane & 31;
        float2 a0 = {0.f,0.f}, a1 = {0.f,0.f};
        int j = lo;
        while (j < hi) {
            int cnt = hi - j; if (cnt > 64) cnt = 64;
            int myidx = (lane < cnt) ? csrc[j + lane] : 0;
            int k = 0;
            for (; k + 4 <= cnt; k += 4) {
                int s0 = __shfl(myidx, k + hf);
                int s1 = __shfl(myidx, k + 2 + hf);
                float2 v0 = h2f2(H[(size_t)s0 * 32 + l32]);
                float2 v1 = h2f2(H[(size_t)s1 * 32 + l32]);
                a0.x += v0.x; a0.y += v0.y;
                a1.x += v1.x; a1.y += v1.y;
            }
            for (; k + 2 <= cnt; k += 2) {
                int s = __shfl(myidx, k + hf);
                float2 v = h2f2(H[(size_t)s * 32 + l32]);
                a0.x += v.x; a0.y += v.y;
            }
            if (k < cnt) {
                int s = __shfl(myidx, k);
                if (hf == 0) {
                    float2 v = h2f2(H[(size_t)s * 32 + l32]);
                    a1.x += v.x; a1.y += v.y;
                }
            }
            j += cnt;
        }
        a0.x += a1.x; a0.y += a1.y;
        a0.x += __shfl_xor(a0.x, 32);
        a0.y += __shfl_xor(a0.y, 32);
        if (lane < 32) reinterpret_cast<float2*>(aggH)[(size_t)w * 32 + l32] = a0;
    }
}

// ---------------------------------------------------------------- dense MFMA (split A AND W)
// out = [relu]( [h|aggH|aggE] @ W^T + b ); X,W split hi/lo bf16:
// acc += al*wh + ah*wl + ah*wh  -> ~fp32 precision. Optional fp16 shadow copy of out.
template <int DIN, int DOUT, bool RELU, bool WF16>
__global__ __launch_bounds__(256) void dense_mfma(
    const float* __restrict__ h, const float* __restrict__ aggH,
    const float* __restrict__ aggE, const ushort* __restrict__ Whi,
    const ushort* __restrict__ Wlo, const float* __restrict__ bias,
    float* __restrict__ out, ushort* __restrict__ out16) {
    constexpr int HCH = DIN / 32;
    constexpr int NCH = 2 * HCH + 1;
    constexpr int KPAD = NCH * 32;
    constexpr int NSUB = DOUT / 16;
    constexpr int WREP = DOUT / 64;
    constexpr int SX = 40;              // LDS stride in ushort

    __shared__ ushort Xhi[64 * SX];
    __shared__ ushort Xlo[64 * SX];
    __shared__ ushort Wh[DOUT * SX];
    __shared__ ushort Wl[DOUT * SX];

    const int t = threadIdx.x;
    const int lane = t & 63, wid = t >> 6;
    const int row0 = blockIdx.x * 64;
    const int rb = wid * 16;

    const int sr = t >> 2, sg = t & 3;

    f32x4 acc[NSUB];
#pragma unroll
    for (int s = 0; s < NSUB; ++s) acc[s] = (f32x4){0.f, 0.f, 0.f, 0.f};

    auto loadX = [&](int c, float4& v0, float4& v1) {
        int grow = row0 + sr;
        v0 = (float4){0.f, 0.f, 0.f, 0.f};
        v1 = (float4){0.f, 0.f, 0.f, 0.f};
        if (grow < NN) {
            if (c < HCH) {
                const float* p = h + (size_t)grow * DIN + c * 32 + sg * 8;
                v0 = *reinterpret_cast<const float4*>(p);
                v1 = *reinterpret_cast<const float4*>(p + 4);
            } else if (c < 2 * HCH) {
                const float* p = aggH + (size_t)grow * DIN + (c - HCH) * 32 + sg * 8;
                v0 = *reinterpret_cast<const float4*>(p);
                v1 = *reinterpret_cast<const float4*>(p + 4);
            } else if (sg == 0) {
                const float* p = aggE + (size_t)grow * 8;
                v0 = *reinterpret_cast<const float4*>(p);
                v1 = *reinterpret_cast<const float4*>(p + 4);
            }
        }
    };

    float4 x0, x1;
    loadX(0, x0, x1);
    uint4 wrh[WREP], wrl[WREP];
#pragma unroll
    for (int r = 0; r < WREP; ++r) {
        int idx = r * 256 + t, col = idx >> 2, g = idx & 3;
        wrh[r] = *reinterpret_cast<const uint4*>(Whi + (size_t)col * KPAD + g * 8);
        wrl[r] = *reinterpret_cast<const uint4*>(Wlo + (size_t)col * KPAD + g * 8);
    }

    for (int c = 0; c < NCH; ++c) {
        uint4 hq, lq;
        split2(x0.x, x0.y, hq.x, lq.x);
        split2(x0.z, x0.w, hq.y, lq.y);
        split2(x1.x, x1.y, hq.z, lq.z);
        split2(x1.z, x1.w, hq.w, lq.w);
        *reinterpret_cast<uint4*>(Xhi + sr * SX + sg * 8) = hq;
        *reinterpret_cast<uint4*>(Xlo + sr * SX + sg * 8) = lq;
#pragma unroll
        for (int r = 0; r < WREP; ++r) {
            int idx = r * 256 + t, col = idx >> 2, g = idx & 3;
            *reinterpret_cast<uint4*>(Wh + col * SX + g * 8) = wrh[r];
            *reinterpret_cast<uint4*>(Wl + col * SX + g * 8) = wrl[r];
        }
        if (c + 1 < NCH) {
            loadX(c + 1, x0, x1);
#pragma unroll
            for (int r = 0; r < WREP; ++r) {
                int idx = r * 256 + t, col = idx >> 2, g = idx & 3;
                wrh[r] = *reinterpret_cast<const uint4*>(
                    Whi + (size_t)col * KPAD + (c + 1) * 32 + g * 8);
                wrl[r] = *reinterpret_cast<const uint4*>(
                    Wlo + (size_t)col * KPAD + (c + 1) * 32 + g * 8);
            }
        }
        __syncthreads();
        const int arow = rb + (lane & 15);
        const int kg = (lane >> 4) * 8;
        bf16x8 ah = *reinterpret_cast<const bf16x8*>(Xhi + arow * SX + kg);
        bf16x8 al = *reinterpret_cast<const bf16x8*>(Xlo + arow * SX + kg);
#pragma unroll
        for (int s = 0; s < NSUB; ++s) {
            int col = s * 16 + (lane & 15);
            bf16x8 wh = *reinterpret_cast<const bf16x8*>(Wh + col * SX + kg);
            bf16x8 wl = *reinterpret_cast<const bf16x8*>(Wl + col * SX + kg);
            acc[s] = __builtin_amdgcn_mfma_f32_16x16x32_bf16(al, wh, acc[s], 0, 0, 0);
            acc[s] = __builtin_amdgcn_mfma_f32_16x16x32_bf16(ah, wl, acc[s], 0, 0, 0);
            acc[s] = __builtin_amdgcn_mfma_f32_16x16x32_bf16(ah, wh, acc[s], 0, 0, 0);
        }
        __syncthreads();
    }

    const int ocol = lane & 15;
    const int rq = lane >> 4;
#pragma unroll
    for (int s = 0; s < NSUB; ++s) {
        float bv = bias[s * 16 + ocol];
#pragma unroll
        for (int r = 0; r < 4; ++r) {
            int grow = row0 + rb + rq * 4 + r;
            if (grow < NN) {
                float v = acc[s][r] + bv;
                if (RELU) v = v > 0.f ? v : 0.f;
                out[(size_t)grow * DOUT + s * 16 + ocol] = v;
                if constexpr (WF16)
                    out16[(size_t)grow * DOUT + s * 16 + ocol] = f2h(v);
            }
        }
    }
}

// ---------------------------------------------------------------- final linear (fp32 h)
__global__ void final_kernel(const float* __restrict__ h, const float* __restrict__ Wc,
                             const float* __restrict__ bc, float* __restrict__ out) {
    int w = blockIdx.x * (blockDim.x >> 6) + (threadIdx.x >> 6);
    int lane = threadIdx.x & 63;
    if (w >= NN) return;
    const float2* H = reinterpret_cast<const float2*>(h);
    const float2* W = reinterpret_cast<const float2*>(Wc);
    float2 hv = H[(size_t)w * 64 + lane];
    float2 wv = W[lane];
    float p = hv.x * wv.x + hv.y * wv.y;
#pragma unroll
    for (int off = 32; off; off >>= 1) p += __shfl_down(p, off);
    if (lane == 0) out[w] = p + bc[0];
}

// ---------------------------------------------------------------- launch
extern "C" void kernel_launch(void* const* d_in, const int* in_sizes, int n_in,
                              void* d_out, int out_size, void* d_ws, size_t ws_size,
                              hipStream_t stream) {
    const float* x   = (const float*)d_in[0];
    const float* ea  = (const float*)d_in[1];
    const int*   src = (const int*)d_in[2];
    const int*   dst = (const int*)d_in[3];
    const float* Ws[5]; const float* Wm[5]; const float* bb[5];
    for (int i = 0; i < 5; ++i) {
        Ws[i] = (const float*)d_in[4 + 3 * i];
        Wm[i] = (const float*)d_in[5 + 3 * i];
        bb[i] = (const float*)d_in[6 + 3 * i];
    }
    const float* Wc = (const float*)d_in[19];
    const float* bc = (const float*)d_in[20];
    float* out = (float*)d_out;

    size_t off = 0;
    auto alloc = [&](size_t bytes) {
        void* p = (char*)d_ws + off;
        off += (bytes + 255) & ~(size_t)255;
        return p;
    };
    float* hA       = (float*)alloc((size_t)NN * 128 * 4);
    float* hB       = (float*)alloc((size_t)NN * 128 * 4);
    float* aggH     = (float*)alloc((size_t)NN * 128 * 4);
    float* aggE     = (float*)alloc((size_t)NN * 8 * 4);
    ushort* hA16    = (ushort*)alloc((size_t)NN * 128 * 2);
    ushort* hB16    = (ushort*)alloc((size_t)NN * 128 * 2);
    ushort* Wh0     = (ushort*)alloc((size_t)64 * 96 * 2);
    ushort* Wl0     = (ushort*)alloc((size_t)64 * 96 * 2);
    ushort* Wh1     = (ushort*)alloc((size_t)128 * 160 * 2);
    ushort* Wl1     = (ushort*)alloc((size_t)128 * 160 * 2);
    ushort* Wh2     = (ushort*)alloc((size_t)128 * 288 * 2);
    ushort* Wl2     = (ushort*)alloc((size_t)128 * 288 * 2);
    ushort* Wh3     = (ushort*)alloc((size_t)128 * 288 * 2);
    ushort* Wl3     = (ushort*)alloc((size_t)128 * 288 * 2);
    ushort* Wh4     = (ushort*)alloc((size_t)128 * 288 * 2);
    ushort* Wl4     = (ushort*)alloc((size_t)128 * 288 * 2);
    int* deg        = (int*)alloc((size_t)(NN + 1) * 4);
    int* row_start  = (int*)alloc((size_t)(NN + 1) * 4);
    int* cursor     = (int*)alloc((size_t)NN * 4);
    int* csr_src    = (int*)alloc((size_t)NE * 4);
    int* bsum       = (int*)alloc((size_t)SCAN_NB * 4);
    int* boff       = (int*)alloc((size_t)SCAN_NB * 4);
    (void)ws_size; (void)in_sizes; (void)n_in; (void)out_size;

    // CSR build + aggE (fused atomics)
    zero2_kernel<<<(NN * 8 + 255) / 256, 256, 0, stream>>>(deg, aggE);
    deg_agge_kernel<<<(NE + 255) / 256, 256, 0, stream>>>(dst, ea, deg, aggE, NE);
    scan1_kernel<<<SCAN_NB, 256, 0, stream>>>(deg, row_start, bsum);
    scan2_kernel<<<1, 256, 0, stream>>>(bsum, boff);
    scan3_kernel<<<SCAN_NB, 256, 0, stream>>>(row_start, boff, cursor);
    fill_kernel<<<(NE + 255) / 256, 256, 0, stream>>>(src, dst, cursor, csr_src, NE);

    // weight prep (bf16 hi/lo, transposed, K-padded)
    prep_w_kernel<<<(64 * 96 + 255) / 256, 256, 0, stream>>>(Ws[0], Wm[0], Wh0, Wl0, 32, 64, 96);
    prep_w_kernel<<<(128 * 160 + 255) / 256, 256, 0, stream>>>(Ws[1], Wm[1], Wh1, Wl1, 64, 128, 160);
    prep_w_kernel<<<(128 * 288 + 255) / 256, 256, 0, stream>>>(Ws[2], Wm[2], Wh2, Wl2, 128, 128, 288);
    prep_w_kernel<<<(128 * 288 + 255) / 256, 256, 0, stream>>>(Ws[3], Wm[3], Wh3, Wl3, 128, 128, 288);
    prep_w_kernel<<<(128 * 288 + 255) / 256, 256, 0, stream>>>(Ws[4], Wm[4], Wh4, Wl4, 128, 128, 288);

    const int GRID_W = (NN + 3) / 4;
    const int GRID_D = (NN + 63) / 64;

    // layer 0: 32 -> 64 (fp32 x gather; dense writes fp32 hA + fp16 hA16)
    aggh32_kernel<<<GRID_W, 256, 0, stream>>>(x, row_start, csr_src, aggH);
    dense_mfma<32, 64, true, true><<<GRID_D, 256, 0, stream>>>(
        x, aggH, aggE, Wh0, Wl0, bb[0], hA, hA16);
    // layer 1: 64 -> 128
    aggh16_kernel<64><<<GRID_W, 256, 0, stream>>>(hA16, row_start, csr_src, aggH);
    dense_mfma<64, 128, true, true><<<GRID_D, 256, 0, stream>>>(
        hA, aggH, aggE, Wh1, Wl1, bb[1], hB, hB16);
    // layer 2
    aggh16_kernel<128><<<GRID_W, 256, 0, stream>>>(hB16, row_start, csr_src, aggH);
    dense_mfma<128, 128, true, true><<<GRID_D, 256, 0, stream>>>(
        hB, aggH, aggE, Wh2, Wl2, bb[2], hA, hA16);
    // layer 3
    aggh16_kernel<128><<<GRID_W, 256, 0, stream>>>(hA16, row_start, csr_src, aggH);
    dense_mfma<128, 128, true, true><<<GRID_D, 256, 0, stream>>>(
        hA, aggH, aggE, Wh3, Wl3, bb[3], hB, hB16);
    // layer 4 (relu; no fp16 shadow needed)
    aggh16_kernel<128><<<GRID_W, 256, 0, stream>>>(hB16, row_start, csr_src, aggH);
    dense_mfma<128, 128, true, false><<<GRID_D, 256, 0, stream>>>(
        hB, aggH, aggE, Wh4, Wl4, bb[4], hA, nullptr);

    // readout
    final_kernel<<<GRID_W, 256, 0, stream>>>(hA, Wc, bc, out);
}

// Round 9
// 452.264 us; speedup vs baseline: 1.7000x; 1.7000x over previous
//
#include <hip/hip_runtime.h>
#include <hip/hip_bf16.h>
#include <hip/hip_fp16.h>

#define NN 50000
#define NE 800000
#define SCAN_NB ((NN + 255) / 256)   // 196

typedef __attribute__((ext_vector_type(8))) short bf16x8;
typedef __attribute__((ext_vector_type(4))) float f32x4;

__device__ __forceinline__ ushort f2bf(float f) {
    __hip_bfloat16 h = __float2bfloat16(f);
    return *reinterpret_cast<ushort*>(&h);
}
__device__ __forceinline__ float bf2f(ushort u) {
    return __builtin_bit_cast(float, (uint)u << 16);
}
__device__ __forceinline__ void split2(float a, float b, uint& hi, uint& lo) {
    ushort ha = f2bf(a), hb = f2bf(b);
    float fa = bf2f(ha), fb = bf2f(hb);
    ushort la = f2bf(a - fa), lb = f2bf(b - fb);
    hi = (uint)ha | ((uint)hb << 16);
    lo = (uint)la | ((uint)lb << 16);
}
__device__ __forceinline__ ushort f2h(float f) {
    __half h = __float2half(f);
    return __builtin_bit_cast(ushort, h);
}
__device__ __forceinline__ uint packh2(float a, float b) {
    return (uint)f2h(a) | ((uint)f2h(b) << 16);
}
__device__ __forceinline__ float2 h2f2(uint u) {
    __half2 h = __builtin_bit_cast(__half2, u);
    return __half22float2(h);
}

// ---------------------------------------------------------------- utilities
__global__ void zero_int_kernel(int* __restrict__ p, int n) {
    int i = blockIdx.x * blockDim.x + threadIdx.x;
    if (i < n) p[i] = 0;
}

// ---------------------------------------------------------------- CSR build
__global__ void deg_kernel(const int* __restrict__ dst, int* __restrict__ deg, int E) {
    int e = blockIdx.x * blockDim.x + threadIdx.x;
    if (e < E) atomicAdd(&deg[dst[e]], 1);
}

__global__ void scan1_kernel(const int* __restrict__ deg, int* __restrict__ pre,
                             int* __restrict__ bsum) {
    __shared__ int sm[256];
    int t = threadIdx.x;
    int i = blockIdx.x * 256 + t;
    int v = (i < NN) ? deg[i] : 0;
    sm[t] = v;
    __syncthreads();
#pragma unroll
    for (int off = 1; off < 256; off <<= 1) {
        int u = (t >= off) ? sm[t - off] : 0;
        __syncthreads();
        sm[t] += u;
        __syncthreads();
    }
    if (i < NN) pre[i] = sm[t] - v;
    if (t == 255) bsum[blockIdx.x] = sm[255];
}

__global__ void scan2_kernel(const int* __restrict__ bsum, int* __restrict__ boff) {
    __shared__ int sm[256];
    int t = threadIdx.x;
    int v = (t < SCAN_NB) ? bsum[t] : 0;
    sm[t] = v;
    __syncthreads();
#pragma unroll
    for (int off = 1; off < 256; off <<= 1) {
        int u = (t >= off) ? sm[t - off] : 0;
        __syncthreads();
        sm[t] += u;
        __syncthreads();
    }
    if (t < SCAN_NB) boff[t] = sm[t] - v;
}

__global__ void scan3_kernel(int* __restrict__ row_start, const int* __restrict__ boff,
                             int* __restrict__ cursor) {
    int i = blockIdx.x * 256 + threadIdx.x;
    if (i < NN) {
        int r = row_start[i] + boff[blockIdx.x];
        row_start[i] = r;
        cursor[i] = r;
    }
    if (i == 0) row_start[NN] = NE;
}

// fill CSR; permute edge_attr into CSR order as packed fp16 (16B/edge)
__global__ void fill_kernel(const int* __restrict__ src, const int* __restrict__ dst,
                            const float* __restrict__ ea, int* __restrict__ cursor,
                            int* __restrict__ csr_src, ushort* __restrict__ ea_perm, int E) {
    int e = blockIdx.x * blockDim.x + threadIdx.x;
    if (e < E) {
        int d = dst[e];
        int p = atomicAdd(&cursor[d], 1);
        csr_src[p] = src[e];
        const float4* q = reinterpret_cast<const float4*>(ea + (size_t)e * 8);
        float4 q0 = q[0], q1 = q[1];
        uint4 o;
        o.x = packh2(q0.x, q0.y); o.y = packh2(q0.z, q0.w);
        o.z = packh2(q1.x, q1.y); o.w = packh2(q1.z, q1.w);
        *reinterpret_cast<uint4*>(ea_perm + (size_t)p * 8) = o;
    }
}

// ---------------------------------------------------------------- agg_e (contiguous fp16)
__global__ void agge_kernel(const ushort* __restrict__ ea_perm, const int* __restrict__ row_start,
                            float* __restrict__ aggE) {
    int v = blockIdx.x * blockDim.x + threadIdx.x;
    if (v >= NN) return;
    int lo = row_start[v], hi = row_start[v + 1];
    float a[8] = {0.f,0.f,0.f,0.f,0.f,0.f,0.f,0.f};
    float b[8] = {0.f,0.f,0.f,0.f,0.f,0.f,0.f,0.f};
    const uint4* P = reinterpret_cast<const uint4*>(ea_perm);
    int j = lo;
    for (; j + 2 <= hi; j += 2) {
        uint4 u0 = P[j], u1 = P[j + 1];
        float2 p0 = h2f2(u0.x), p1 = h2f2(u0.y), p2 = h2f2(u0.z), p3 = h2f2(u0.w);
        float2 q0 = h2f2(u1.x), q1 = h2f2(u1.y), q2 = h2f2(u1.z), q3 = h2f2(u1.w);
        a[0] += p0.x; a[1] += p0.y; a[2] += p1.x; a[3] += p1.y;
        a[4] += p2.x; a[5] += p2.y; a[6] += p3.x; a[7] += p3.y;
        b[0] += q0.x; b[1] += q0.y; b[2] += q1.x; b[3] += q1.y;
        b[4] += q2.x; b[5] += q2.y; b[6] += q3.x; b[7] += q3.y;
    }
    if (j < hi) {
        uint4 u0 = P[j];
        float2 p0 = h2f2(u0.x), p1 = h2f2(u0.y), p2 = h2f2(u0.z), p3 = h2f2(u0.w);
        a[0] += p0.x; a[1] += p0.y; a[2] += p1.x; a[3] += p1.y;
        a[4] += p2.x; a[5] += p2.y; a[6] += p3.x; a[7] += p3.y;
    }
#pragma unroll
    for (int i = 0; i < 8; ++i) a[i] += b[i];
    float4* o = reinterpret_cast<float4*>(aggE + (size_t)v * 8);
    o[0] = (float4){a[0], a[1], a[2], a[3]};
    o[1] = (float4){a[4], a[5], a[6], a[7]};
}

// ---------------------------------------------------------------- agg_h layer0 (fp32 x, DIN=32)
__global__ void aggh32_kernel(const float* __restrict__ h, const int* __restrict__ row_start,
                              const int* __restrict__ csrc, float* __restrict__ aggH) {
    int w = blockIdx.x * (blockDim.x >> 6) + (threadIdx.x >> 6);
    int lane = threadIdx.x & 63;
    if (w >= NN) return;
    int lo = row_start[w], hi = row_start[w + 1];
    int half = lane >> 5;
    int l32 = lane & 31;
    float a0 = 0.f, a1 = 0.f, a2 = 0.f, a3 = 0.f;
    int j = lo;
    while (j < hi) {
        int cnt = hi - j; if (cnt > 64) cnt = 64;
        int myidx = (lane < cnt) ? csrc[j + lane] : 0;
        int k = 0;
        for (; k + 8 <= cnt; k += 8) {
            int s0 = __shfl(myidx, k + half);
            int s1 = __shfl(myidx, k + 2 + half);
            int s2 = __shfl(myidx, k + 4 + half);
            int s3 = __shfl(myidx, k + 6 + half);
            a0 += h[(size_t)s0 * 32 + l32];
            a1 += h[(size_t)s1 * 32 + l32];
            a2 += h[(size_t)s2 * 32 + l32];
            a3 += h[(size_t)s3 * 32 + l32];
        }
        for (; k + 2 <= cnt; k += 2) {
            int s = __shfl(myidx, k + half);
            a0 += h[(size_t)s * 32 + l32];
        }
        if (k < cnt) {
            int s = __shfl(myidx, k);
            if (half == 0) a1 += h[(size_t)s * 32 + l32];
        }
        j += cnt;
    }
    a0 = (a0 + a1) + (a2 + a3);
    a0 += __shfl_xor(a0, 32);
    if (lane < 32) aggH[(size_t)w * 32 + lane] = a0;
}

// ---------------------------------------------------------------- agg_h fp16 gather (DIN=64/128)
template <int DIN>
__global__ void aggh16_kernel(const ushort* __restrict__ h16, const int* __restrict__ row_start,
                              const int* __restrict__ csrc, float* __restrict__ aggH) {
    int w = blockIdx.x * (blockDim.x >> 6) + (threadIdx.x >> 6);
    int lane = threadIdx.x & 63;
    if (w >= NN) return;
    int lo = row_start[w], hi = row_start[w + 1];
    const uint* H = reinterpret_cast<const uint*>(h16);

    if constexpr (DIN == 128) {
        float2 a0 = {0.f,0.f}, a1 = {0.f,0.f}, a2 = {0.f,0.f}, a3 = {0.f,0.f};
        int j = lo;
        while (j < hi) {
            int cnt = hi - j; if (cnt > 64) cnt = 64;
            int myidx = (lane < cnt) ? csrc[j + lane] : 0;
            int k = 0;
            for (; k + 4 <= cnt; k += 4) {
                int s0 = __shfl(myidx, k);
                int s1 = __shfl(myidx, k + 1);
                int s2 = __shfl(myidx, k + 2);
                int s3 = __shfl(myidx, k + 3);
                float2 v0 = h2f2(H[(size_t)s0 * 64 + lane]);
                float2 v1 = h2f2(H[(size_t)s1 * 64 + lane]);
                float2 v2 = h2f2(H[(size_t)s2 * 64 + lane]);
                float2 v3 = h2f2(H[(size_t)s3 * 64 + lane]);
                a0.x += v0.x; a0.y += v0.y;
                a1.x += v1.x; a1.y += v1.y;
                a2.x += v2.x; a2.y += v2.y;
                a3.x += v3.x; a3.y += v3.y;
            }
            for (; k < cnt; ++k) {
                int s = __shfl(myidx, k);
                float2 v = h2f2(H[(size_t)s * 64 + lane]);
                a0.x += v.x; a0.y += v.y;
            }
            j += cnt;
        }
        a0.x += a1.x; a0.y += a1.y;
        a2.x += a3.x; a2.y += a3.y;
        a0.x += a2.x; a0.y += a2.y;
        reinterpret_cast<float2*>(aggH)[(size_t)w * 64 + lane] = a0;
    } else {  // DIN == 64: half wave per row; 2 rows per pass
        int hf = lane >> 5, l32 = lane & 31;
        float2 a0 = {0.f,0.f}, a1 = {0.f,0.f};
        int j = lo;
        while (j < hi) {
            int cnt = hi - j; if (cnt > 64) cnt = 64;
            int myidx = (lane < cnt) ? csrc[j + lane] : 0;
            int k = 0;
            for (; k + 4 <= cnt; k += 4) {
                int s0 = __shfl(myidx, k + hf);
                int s1 = __shfl(myidx, k + 2 + hf);
                float2 v0 = h2f2(H[(size_t)s0 * 32 + l32]);
                float2 v1 = h2f2(H[(size_t)s1 * 32 + l32]);
                a0.x += v0.x; a0.y += v0.y;
                a1.x += v1.x; a1.y += v1.y;
            }
            for (; k + 2 <= cnt; k += 2) {
                int s = __shfl(myidx, k + hf);
                float2 v = h2f2(H[(size_t)s * 32 + l32]);
                a0.x += v.x; a0.y += v.y;
            }
            if (k < cnt) {
                int s = __shfl(myidx, k);
                if (hf == 0) {
                    float2 v = h2f2(H[(size_t)s * 32 + l32]);
                    a1.x += v.x; a1.y += v.y;
                }
            }
            j += cnt;
        }
        a0.x += a1.x; a0.y += a1.y;
        a0.x += __shfl_xor(a0.x, 32);
        a0.y += __shfl_xor(a0.y, 32);
        if (lane < 32) reinterpret_cast<float2*>(aggH)[(size_t)w * 32 + l32] = a0;
    }
}

// ---------------------------------------------------------------- weight prep (bf16 hi/lo split)
__global__ void prep_w_kernel(const float* __restrict__ Ws, const float* __restrict__ Wm,
                              ushort* __restrict__ Whi, ushort* __restrict__ Wlo,
                              int DIN, int DOUT, int KPAD) {
    int gid = blockIdx.x * blockDim.x + threadIdx.x;
    if (gid >= DOUT * KPAD) return;
    int c = gid / KPAD, k = gid % KPAD;
    float v = 0.f;
    if (k < DIN) v = Ws[(size_t)k * DOUT + c];
    else if (k < 2 * DIN + 8) v = Wm[(size_t)(k - DIN) * DOUT + c];
    ushort h = f2bf(v);
    Whi[gid] = h;
    Wlo[gid] = f2bf(v - bf2f(h));
}

// ---------------------------------------------------------------- dense MFMA (split A AND W)
template <int DIN, int DOUT, bool RELU, bool WF16>
__global__ __launch_bounds__(256) void dense_mfma(
    const float* __restrict__ h, const float* __restrict__ aggH,
    const float* __restrict__ aggE, const ushort* __restrict__ Whi,
    const ushort* __restrict__ Wlo, const float* __restrict__ bias,
    float* __restrict__ out, ushort* __restrict__ out16) {
    constexpr int HCH = DIN / 32;
    constexpr int NCH = 2 * HCH + 1;
    constexpr int KPAD = NCH * 32;
    constexpr int NSUB = DOUT / 16;
    constexpr int WREP = DOUT / 64;
    constexpr int SX = 40;

    __shared__ ushort Xhi[64 * SX];
    __shared__ ushort Xlo[64 * SX];
    __shared__ ushort Wh[DOUT * SX];
    __shared__ ushort Wl[DOUT * SX];

    const int t = threadIdx.x;
    const int lane = t & 63, wid = t >> 6;
    const int row0 = blockIdx.x * 64;
    const int rb = wid * 16;

    const int sr = t >> 2, sg = t & 3;

    f32x4 acc[NSUB];
#pragma unroll
    for (int s = 0; s < NSUB; ++s) acc[s] = (f32x4){0.f, 0.f, 0.f, 0.f};

    auto loadX = [&](int c, float4& v0, float4& v1) {
        int grow = row0 + sr;
        v0 = (float4){0.f, 0.f, 0.f, 0.f};
        v1 = (float4){0.f, 0.f, 0.f, 0.f};
        if (grow < NN) {
            if (c < HCH) {
                const float* p = h + (size_t)grow * DIN + c * 32 + sg * 8;
                v0 = *reinterpret_cast<const float4*>(p);
                v1 = *reinterpret_cast<const float4*>(p + 4);
            } else if (c < 2 * HCH) {
                const float* p = aggH + (size_t)grow * DIN + (c - HCH) * 32 + sg * 8;
                v0 = *reinterpret_cast<const float4*>(p);
                v1 = *reinterpret_cast<const float4*>(p + 4);
            } else if (sg == 0) {
                const float* p = aggE + (size_t)grow * 8;
                v0 = *reinterpret_cast<const float4*>(p);
                v1 = *reinterpret_cast<const float4*>(p + 4);
            }
        }
    };

    float4 x0, x1;
    loadX(0, x0, x1);
    uint4 wrh[WREP], wrl[WREP];
#pragma unroll
    for (int r = 0; r < WREP; ++r) {
        int idx = r * 256 + t, col = idx >> 2, g = idx & 3;
        wrh[r] = *reinterpret_cast<const uint4*>(Whi + (size_t)col * KPAD + g * 8);
        wrl[r] = *reinterpret_cast<const uint4*>(Wlo + (size_t)col * KPAD + g * 8);
    }

    for (int c = 0; c < NCH; ++c) {
        uint4 hq, lq;
        split2(x0.x, x0.y, hq.x, lq.x);
        split2(x0.z, x0.w, hq.y, lq.y);
        split2(x1.x, x1.y, hq.z, lq.z);
        split2(x1.z, x1.w, hq.w, lq.w);
        *reinterpret_cast<uint4*>(Xhi + sr * SX + sg * 8) = hq;
        *reinterpret_cast<uint4*>(Xlo + sr * SX + sg * 8) = lq;
#pragma unroll
        for (int r = 0; r < WREP; ++r) {
            int idx = r * 256 + t, col = idx >> 2, g = idx & 3;
            *reinterpret_cast<uint4*>(Wh + col * SX + g * 8) = wrh[r];
            *reinterpret_cast<uint4*>(Wl + col * SX + g * 8) = wrl[r];
        }
        if (c + 1 < NCH) {
            loadX(c + 1, x0, x1);
#pragma unroll
            for (int r = 0; r < WREP; ++r) {
                int idx = r * 256 + t, col = idx >> 2, g = idx & 3;
                wrh[r] = *reinterpret_cast<const uint4*>(
                    Whi + (size_t)col * KPAD + (c + 1) * 32 + g * 8);
                wrl[r] = *reinterpret_cast<const uint4*>(
                    Wlo + (size_t)col * KPAD + (c + 1) * 32 + g * 8);
            }
        }
        __syncthreads();
        const int arow = rb + (lane & 15);
        const int kg = (lane >> 4) * 8;
        bf16x8 ah = *reinterpret_cast<const bf16x8*>(Xhi + arow * SX + kg);
        bf16x8 al = *reinterpret_cast<const bf16x8*>(Xlo + arow * SX + kg);
#pragma unroll
        for (int s = 0; s < NSUB; ++s) {
            int col = s * 16 + (lane & 15);
            bf16x8 wh = *reinterpret_cast<const bf16x8*>(Wh + col * SX + kg);
            bf16x8 wl = *reinterpret_cast<const bf16x8*>(Wl + col * SX + kg);
            acc[s] = __builtin_amdgcn_mfma_f32_16x16x32_bf16(al, wh, acc[s], 0, 0, 0);
            acc[s] = __builtin_amdgcn_mfma_f32_16x16x32_bf16(ah, wl, acc[s], 0, 0, 0);
            acc[s] = __builtin_amdgcn_mfma_f32_16x16x32_bf16(ah, wh, acc[s], 0, 0, 0);
        }
        __syncthreads();
    }

    const int ocol = lane & 15;
    const int rq = lane >> 4;
#pragma unroll
    for (int s = 0; s < NSUB; ++s) {
        float bv = bias[s * 16 + ocol];
#pragma unroll
        for (int r = 0; r < 4; ++r) {
            int grow = row0 + rb + rq * 4 + r;
            if (grow < NN) {
                float v = acc[s][r] + bv;
                if (RELU) v = v > 0.f ? v : 0.f;
                out[(size_t)grow * DOUT + s * 16 + ocol] = v;
                if constexpr (WF16)
                    out16[(size_t)grow * DOUT + s * 16 + ocol] = f2h(v);
            }
        }
    }
}

// ---------------------------------------------------------------- final linear (fp32 h)
__global__ void final_kernel(const float* __restrict__ h, const float* __restrict__ Wc,
                             const float* __restrict__ bc, float* __restrict__ out) {
    int w = blockIdx.x * (blockDim.x >> 6) + (threadIdx.x >> 6);
    int lane = threadIdx.x & 63;
    if (w >= NN) return;
    const float2* H = reinterpret_cast<const float2*>(h);
    const float2* W = reinterpret_cast<const float2*>(Wc);
    float2 hv = H[(size_t)w * 64 + lane];
    float2 wv = W[lane];
    float p = hv.x * wv.x + hv.y * wv.y;
#pragma unroll
    for (int off = 32; off; off >>= 1) p += __shfl_down(p, off);
    if (lane == 0) out[w] = p + bc[0];
}

// ---------------------------------------------------------------- launch
extern "C" void kernel_launch(void* const* d_in, const int* in_sizes, int n_in,
                              void* d_out, int out_size, void* d_ws, size_t ws_size,
                              hipStream_t stream) {
    const float* x   = (const float*)d_in[0];
    const float* ea  = (const float*)d_in[1];
    const int*   src = (const int*)d_in[2];
    const int*   dst = (const int*)d_in[3];
    const float* Ws[5]; const float* Wm[5]; const float* bb[5];
    for (int i = 0; i < 5; ++i) {
        Ws[i] = (const float*)d_in[4 + 3 * i];
        Wm[i] = (const float*)d_in[5 + 3 * i];
        bb[i] = (const float*)d_in[6 + 3 * i];
    }
    const float* Wc = (const float*)d_in[19];
    const float* bc = (const float*)d_in[20];
    float* out = (float*)d_out;

    size_t off = 0;
    auto alloc = [&](size_t bytes) {
        void* p = (char*)d_ws + off;
        off += (bytes + 255) & ~(size_t)255;
        return p;
    };
    float* hA       = (float*)alloc((size_t)NN * 128 * 4);
    float* hB       = (float*)alloc((size_t)NN * 128 * 4);
    float* aggH     = (float*)alloc((size_t)NN * 128 * 4);
    float* aggE     = (float*)alloc((size_t)NN * 8 * 4);
    ushort* hA16    = (ushort*)alloc((size_t)NN * 128 * 2);
    ushort* hB16    = (ushort*)alloc((size_t)NN * 128 * 2);  // aliases ea_perm
    ushort* Wh0     = (ushort*)alloc((size_t)64 * 96 * 2);
    ushort* Wl0     = (ushort*)alloc((size_t)64 * 96 * 2);
    ushort* Wh1     = (ushort*)alloc((size_t)128 * 160 * 2);
    ushort* Wl1     = (ushort*)alloc((size_t)128 * 160 * 2);
    ushort* Wh2     = (ushort*)alloc((size_t)128 * 288 * 2);
    ushort* Wl2     = (ushort*)alloc((size_t)128 * 288 * 2);
    ushort* Wh3     = (ushort*)alloc((size_t)128 * 288 * 2);
    ushort* Wl3     = (ushort*)alloc((size_t)128 * 288 * 2);
    ushort* Wh4     = (ushort*)alloc((size_t)128 * 288 * 2);
    ushort* Wl4     = (ushort*)alloc((size_t)128 * 288 * 2);
    int* deg        = (int*)alloc((size_t)(NN + 1) * 4);
    int* row_start  = (int*)alloc((size_t)(NN + 1) * 4);
    int* cursor     = (int*)alloc((size_t)NN * 4);
    int* csr_src    = (int*)alloc((size_t)NE * 4);
    int* bsum       = (int*)alloc((size_t)SCAN_NB * 4);
    int* boff       = (int*)alloc((size_t)SCAN_NB * 4);
    ushort* ea_perm = hB16;  // NE*8*2 == NN*128*2; dead before hB16 first written
    (void)ws_size; (void)in_sizes; (void)n_in; (void)out_size;

    // CSR build + fp16 edge-attr permute
    zero_int_kernel<<<(NN + 255) / 256, 256, 0, stream>>>(deg, NN);
    deg_kernel<<<(NE + 255) / 256, 256, 0, stream>>>(dst, deg, NE);
    scan1_kernel<<<SCAN_NB, 256, 0, stream>>>(deg, row_start, bsum);
    scan2_kernel<<<1, 256, 0, stream>>>(bsum, boff);
    scan3_kernel<<<SCAN_NB, 256, 0, stream>>>(row_start, boff, cursor);
    fill_kernel<<<(NE + 255) / 256, 256, 0, stream>>>(src, dst, ea, cursor, csr_src, ea_perm, NE);

    agge_kernel<<<(NN + 255) / 256, 256, 0, stream>>>(ea_perm, row_start, aggE);

    // weight prep (bf16 hi/lo, transposed, K-padded)
    prep_w_kernel<<<(64 * 96 + 255) / 256, 256, 0, stream>>>(Ws[0], Wm[0], Wh0, Wl0, 32, 64, 96);
    prep_w_kernel<<<(128 * 160 + 255) / 256, 256, 0, stream>>>(Ws[1], Wm[1], Wh1, Wl1, 64, 128, 160);
    prep_w_kernel<<<(128 * 288 + 255) / 256, 256, 0, stream>>>(Ws[2], Wm[2], Wh2, Wl2, 128, 128, 288);
    prep_w_kernel<<<(128 * 288 + 255) / 256, 256, 0, stream>>>(Ws[3], Wm[3], Wh3, Wl3, 128, 128, 288);
    prep_w_kernel<<<(128 * 288 + 255) / 256, 256, 0, stream>>>(Ws[4], Wm[4], Wh4, Wl4, 128, 128, 288);

    const int GRID_W = (NN + 3) / 4;
    const int GRID_D = (NN + 63) / 64;

    // layer 0: 32 -> 64 (fp32 x gather)
    aggh32_kernel<<<GRID_W, 256, 0, stream>>>(x, row_start, csr_src, aggH);
    dense_mfma<32, 64, true, true><<<GRID_D, 256, 0, stream>>>(
        x, aggH, aggE, Wh0, Wl0, bb[0], hA, hA16);
    // layer 1: 64 -> 128
    aggh16_kernel<64><<<GRID_W, 256, 0, stream>>>(hA16, row_start, csr_src, aggH);
    dense_mfma<64, 128, true, true><<<GRID_D, 256, 0, stream>>>(
        hA, aggH, aggE, Wh1, Wl1, bb[1], hB, hB16);
    // layer 2
    aggh16_kernel<128><<<GRID_W, 256, 0, stream>>>(hB16, row_start, csr_src, aggH);
    dense_mfma<128, 128, true, true><<<GRID_D, 256, 0, stream>>>(
        hB, aggH, aggE, Wh2, Wl2, bb[2], hA, hA16);
    // layer 3
    aggh16_kernel<128><<<GRID_W, 256, 0, stream>>>(hA16, row_start, csr_src, aggH);
    dense_mfma<128, 128, true, true><<<GRID_D, 256, 0, stream>>>(
        hA, aggH, aggE, Wh3, Wl3, bb[3], hB, hB16);
    // layer 4
    aggh16_kernel<128><<<GRID_W, 256, 0, stream>>>(hB16, row_start, csr_src, aggH);
    dense_mfma<128, 128, true, false><<<GRID_D, 256, 0, stream>>>(
        hB, aggH, aggE, Wh4, Wl4, bb[4], hA, nullptr);

    // readout
    final_kernel<<<GRID_W, 256, 0, stream>>>(hA, Wc, bc, out);
}